// Round 1
// baseline (5425.304 us; speedup 1.0000x reference)
//
#include <hip/hip_runtime.h>

typedef _Float16 half_t;
typedef _Float16 f16x8 __attribute__((ext_vector_type(8)));
typedef _Float16 f16x4 __attribute__((ext_vector_type(4)));
typedef float f32x4 __attribute__((ext_vector_type(4)));

#define BB 4
#define NNODE 24
#define NLAYER 64
#define SCALE_QK 0.0625f

// ---- workspace layout (float offsets) ----
#define WS_C     0               // [4][256]
#define WS_N     1024            // 2 x [96][256]
#define N_STRIDE   24576
#define WS_QKV   50176           // 2 x [96][768]
#define QKV_STRIDE 73728
#define WS_E     197632          // 2 x [2304][256]
#define E_STRIDE   589824
#define WS_WTF   1377280         // f16 region (as float index)
// f16 offsets inside a slot
#define SLOT_F16 1376256
#define OFF_QKVT 0               // [768][256]
#define OFF_NOT  196608          // [256][256]
#define OFF_EOT  262144          // [256][256]
#define OFF_MN1T 327680          // [1024][256]
#define OFF_MN2T 589824          // [256][1024]
#define OFF_ME1T 851968          // [1024][256]
#define OFF_ME2T 1114112         // [256][1024]
#define OFF_INE2T  (3*SLOT_F16)          // [256][256]
#define OFF_OUTE1T (3*SLOT_F16 + 65536)  // [256][256]

#define SMEM_BYTES 114816

struct Params {
  const float *nodes, *edges; const int* conds;
  const float *inN_w1,*inN_b1,*inN_w2,*inN_b2;
  const float *inE_w1,*inE_b1,*inE_w2,*inE_b2;
  const float *inC_w1,*inC_b1,*inC_w2,*inC_b2;
  const float *qkv_w,*qkv_b,*no_w,*no_b,*eo_w,*eo_b;
  const float *ln1n_g,*ln1n_b,*ln1e_g,*ln1e_b;
  const float *mn_w1,*mn_b1,*mn_w2,*mn_b2,*me_w1,*me_b1,*me_w2,*me_b2;
  const float *ln2n_g,*ln2n_b,*ln2e_g,*ln2e_b;
  const float *outN_w1,*outN_b1,*outN_w2,*outN_b2,*outE_w1,*outE_b1,*outE_w2,*outE_b2;
  float* ws; float* out;
};

// ---- generic per-WG MFMA GEMM: A (f16, LDS, swizzled) x WT (f16 global [N][K]) ----
// 8 waves; wave wv owns n-tiles {n*8+wv}. acc[n][m] = 16x16 C-tile (mt m).
template<int NTW, int KT, int MT, int LDA, int LDB>
__device__ __forceinline__ void run_gemm(const half_t* __restrict__ WT,
                                         const char* __restrict__ A,
                                         f32x4 (&acc)[NTW][MT]) {
  const int lane = threadIdx.x & 63;
  const int wv = threadIdx.x >> 6;
  const int l15 = lane & 15;
  const int kg = lane >> 4;
#pragma unroll
  for (int n = 0; n < NTW; ++n)
#pragma unroll
    for (int m = 0; m < MT; ++m) {
      f32x4 z = {0.f, 0.f, 0.f, 0.f};
      acc[n][m] = z;
    }
  for (int kt = 0; kt < KT; ++kt) {
    const int k0 = kt * 32 + kg * 8;
    f16x8 a[MT];
#pragma unroll
    for (int m = 0; m < MT; ++m) {
      const int row = m * 16 + l15;
      a[m] = *(const f16x8*)(A + row * (LDA * 2) + ((k0 * 2) ^ ((row & 7) << 4)));
    }
#pragma unroll
    for (int n = 0; n < NTW; ++n) {
      const half_t* bp = WT + (size_t)((n * 8 + wv) * 16 + l15) * LDB + k0;
      f16x8 b = *(const f16x8*)bp;
#pragma unroll
      for (int m = 0; m < MT; ++m)
        acc[n][m] = __builtin_amdgcn_mfma_f32_16x16x32_f16(a[m], b, acc[n][m], 0, 0, 0);
    }
  }
}

// ---- 64x64 transpose+convert fp32 -> f16 tile ----
__device__ void conv_matrix_tile(const float* __restrict__ src, half_t* __restrict__ dst,
                                 int K, int Nn, int tk, int tn, char* smem) {
  float* tl = (float*)smem;  // [64][65]
  const int t = threadIdx.x;
  const int c = t & 63;
  const int r0 = t >> 6;
  for (int r = r0; r < 64; r += 8)
    tl[r * 65 + c] = src[(size_t)(tk * 64 + r) * Nn + tn * 64 + c];
  __syncthreads();
  for (int r = r0; r < 64; r += 8)
    dst[(size_t)(tn * 64 + r) * K + tk * 64 + c] = (half_t)tl[c * 65 + r];
  __syncthreads();
}

__device__ void conv_layer_tile(const Params& p, half_t* slot, int lw, int tile, char* smem) {
  if (tile < 48)       { conv_matrix_tile(p.qkv_w + (size_t)lw*196608, slot+OFF_QKVT, 256, 768, tile & 3, tile >> 2, smem); }
  else if (tile < 64)  { int t2 = tile-48;  conv_matrix_tile(p.no_w  + (size_t)lw*65536,  slot+OFF_NOT,  256, 256, t2 & 3,  t2 >> 2, smem); }
  else if (tile < 80)  { int t2 = tile-64;  conv_matrix_tile(p.eo_w  + (size_t)lw*65536,  slot+OFF_EOT,  256, 256, t2 & 3,  t2 >> 2, smem); }
  else if (tile < 144) { int t2 = tile-80;  conv_matrix_tile(p.mn_w1 + (size_t)lw*262144, slot+OFF_MN1T, 256, 1024, t2 & 3, t2 >> 2, smem); }
  else if (tile < 208) { int t2 = tile-144; conv_matrix_tile(p.mn_w2 + (size_t)lw*262144, slot+OFF_MN2T, 1024, 256, t2 & 15, t2 >> 4, smem); }
  else if (tile < 272) { int t2 = tile-208; conv_matrix_tile(p.me_w1 + (size_t)lw*262144, slot+OFF_ME1T, 256, 1024, t2 & 3, t2 >> 2, smem); }
  else                 { int t2 = tile-272; conv_matrix_tile(p.me_w2 + (size_t)lw*262144, slot+OFF_ME2T, 1024, 256, t2 & 15, t2 >> 4, smem); }
}

// ================= embed A: cond-MLP + convert W(0), W(1), inE_w2T, outE_w1T ===========
__global__ __launch_bounds__(512) void k_embedA(Params p) {
  __shared__ __align__(16) char smem[SMEM_BYTES];
  const int bid = blockIdx.x, tid = threadIdx.x;
  float* ws = p.ws;
  half_t* wt = (half_t*)(ws + WS_WTF);
  if (bid < 4) {
    const int b = bid;
    const int cond = p.conds[b];
    float* t1 = (float*)smem;
    if (tid < 256) t1[tid] = fmaxf(p.inC_w1[(size_t)cond * 256 + tid] + p.inC_b1[tid], 0.f);
    __syncthreads();
    if (tid < 256) {
      float s = p.inC_b2[tid];
      for (int k = 0; k < 256; ++k) s += t1[k] * p.inC_w2[(size_t)k * 256 + tid];
      ws[WS_C + b * 256 + tid] = fmaxf(s, 0.f);
    }
  } else {
    for (int job = bid - 4; job < 704; job += 64) {
      if (job < 336)      conv_layer_tile(p, wt, 0, job, smem);
      else if (job < 672) conv_layer_tile(p, wt + SLOT_F16, 1, job - 336, smem);
      else if (job < 688) { int t2 = job - 672; conv_matrix_tile(p.inE_w2,  wt + OFF_INE2T,  256, 256, t2 & 3, t2 >> 2, smem); }
      else                { int t2 = job - 688; conv_matrix_tile(p.outE_w1, wt + OFF_OUTE1T, 256, 256, t2 & 3, t2 >> 2, smem); }
    }
  }
}

// ================= embed B: edge embed (MFMA), node embed + qkv(0) =====================
__global__ __launch_bounds__(512) void k_embedB(Params p) {
  __shared__ __align__(16) char smem[SMEM_BYTES];
  const int bid = blockIdx.x, tid = threadIdx.x;
  const int lane = tid & 63, wv = tid >> 6, l15 = lane & 15, kg = lane >> 4;
  float* ws = p.ws;
  half_t* wt = (half_t*)(ws + WS_WTF);
  float* e0 = ws + WS_E;
  float* n0 = ws + WS_N;
  float* qkv0 = ws + WS_QKV;
  if (bid < 96) {
    const int b = bid / NNODE, i = bid % NNODE;
    float* eb = (float*)smem;        // [24][12]
    char* t16 = smem + 2048;         // [32][256] f16
    for (int idx = tid; idx < 24 * 12; idx += 512)
      eb[idx] = p.edges[((size_t)(b * NNODE + i) * NNODE + idx / 12) * 12 + idx % 12];
    __syncthreads();
    for (int idx = tid; idx < 32 * 32; idx += 512) {
      int r = idx >> 5, kb = idx & 31, k0 = kb * 8;
      f16x8 v;
#pragma unroll
      for (int j = 0; j < 8; ++j) v[j] = (half_t)0.f;
      if (r < NNODE) {
#pragma unroll
        for (int j = 0; j < 8; ++j) {
          int col = k0 + j;
          float s = p.inE_b1[col];
          for (int kk = 0; kk < 12; ++kk) s += eb[r * 12 + kk] * p.inE_w1[kk * 256 + col];
          v[j] = (half_t)fmaxf(s, 0.f);
        }
      }
      *(f16x8*)(t16 + r * 512 + ((k0 * 2) ^ ((r & 7) << 4))) = v;
    }
    __syncthreads();
    f32x4 acc[2][2];
    run_gemm<2, 8, 2, 256, 256>(wt + OFF_INE2T, t16, acc);
#pragma unroll
    for (int n = 0; n < 2; ++n) {
      const int col = (n * 8 + wv) * 16 + l15;
#pragma unroll
      for (int m = 0; m < 2; ++m)
#pragma unroll
        for (int r4 = 0; r4 < 4; ++r4) {
          const int row = m * 16 + kg * 4 + r4;
          if (row < NNODE)
            e0[((size_t)(b * NNODE + i) * NNODE + row) * 256 + col] = fmaxf(acc[n][m][r4] + p.inE_b2[col], 0.f);
        }
    }
  } else {
    const int nb = bid - 96, b = nb >> 1, hf = nb & 1, i0 = hf * 12;
    float* nd = (float*)smem;            // [12][16]
    float* t1 = (float*)(smem + 1024);   // [12][257]
    char* nc16 = smem + 16384;           // [16][256] f16
    for (int idx = tid; idx < 12 * 13; idx += 512)
      nd[(idx / 13) * 16 + (idx % 13)] = p.nodes[(size_t)(b * NNODE + i0 + idx / 13) * 13 + idx % 13];
    __syncthreads();
    for (int idx = tid; idx < 12 * 256; idx += 512) {
      int r = idx >> 8, col = idx & 255;
      float s = p.inN_b1[col];
      for (int kk = 0; kk < 13; ++kk) s += nd[r * 16 + kk] * p.inN_w1[kk * 256 + col];
      t1[r * 257 + col] = fmaxf(s, 0.f);
    }
    __syncthreads();
    {
      int col = tid & 255, rh = tid >> 8;
      float a6[6] = {0.f, 0.f, 0.f, 0.f, 0.f, 0.f};
      for (int k = 0; k < 256; ++k) {
        float w = p.inN_w2[(size_t)k * 256 + col];
#pragma unroll
        for (int r = 0; r < 6; ++r) a6[r] += t1[(rh * 6 + r) * 257 + k] * w;
      }
      const float* cb = ws + WS_C + b * 256;
#pragma unroll
      for (int r = 0; r < 6; ++r) {
        int row = rh * 6 + r;
        float y = fmaxf(a6[r] + p.inN_b2[col], 0.f);
        n0[(size_t)(b * NNODE + i0 + row) * 256 + col] = y;
        *(half_t*)(nc16 + row * 512 + ((col * 2) ^ ((row & 7) << 4))) = (half_t)(y + cb[col]);
      }
      if (rh == 0)
        for (int row = 12; row < 16; ++row)
          *(half_t*)(nc16 + row * 512 + ((col * 2) ^ ((row & 7) << 4))) = (half_t)0.f;
    }
    __syncthreads();
    f32x4 accq[6][1];
    run_gemm<6, 8, 1, 256, 256>(wt + OFF_QKVT, nc16, accq);
#pragma unroll
    for (int n = 0; n < 6; ++n) {
      const int col = (n * 8 + wv) * 16 + l15;
#pragma unroll
      for (int r4 = 0; r4 < 4; ++r4) {
        const int row = kg * 4 + r4;
        if (row < 12)
          qkv0[(size_t)(b * NNODE + i0 + row) * 768 + col] = accq[n][0][r4] + p.qkv_b[col];
      }
    }
  }
}

// ================= one transformer layer =====================
__global__ __launch_bounds__(512) void k_layer(Params p, int lyr) {
  __shared__ __align__(16) char smem[SMEM_BYTES];
  const int bid = blockIdx.x, tid = threadIdx.x;
  const int lane = tid & 63, wv = tid >> 6, l15 = lane & 15, kg = lane >> 4;
  const int pin = lyr & 1, pout = pin ^ 1;
  float* ws = p.ws;
  half_t* wt = (half_t*)(ws + WS_WTF);
  const float* qkv_in = ws + WS_QKV + pin * QKV_STRIDE;
  float* qkv_out = ws + WS_QKV + pout * QKV_STRIDE;
  const float* n_in = ws + WS_N + pin * N_STRIDE;
  float* n_out = ws + WS_N + pout * N_STRIDE;
  const float* e_in = ws + WS_E + pin * E_STRIDE;
  float* e_out = ws + WS_E + pout * E_STRIDE;
  const half_t* slot = wt + (size_t)(lyr % 3) * SLOT_F16;

  if (bid < 96) {
    // ---------------- edge path: one (b,i), 24 rows ----------------
    const int b = bid / NNODE, i = bid % NNODE;
    const size_t rowbase = (size_t)(b * NNODE + i) * NNODE;
    float* aef = (float*)smem;     // [32][257] f32 (overlays ne5 after GEMM1)
    char* ne5 = smem;              // [32][256] f16
    char* ae16 = smem + 32896;     // [32][256] f16
    char* hT = smem + 49280;       // [32][1024] f16

    for (int idx = tid; idx < 32 * 32; idx += 512) {
      int r = idx >> 5, kb = idx & 31, k0 = kb * 8;
      f16x8 v;
#pragma unroll
      for (int j = 0; j < 8; ++j) v[j] = (half_t)0.f;
      if (r < NNODE) {
        const float* qp = qkv_in + (size_t)(b * NNODE + i) * 768 + k0;
        const float* kp = qkv_in + (size_t)(b * NNODE + r) * 768 + 256 + k0;
        const float* ep = e_in + (rowbase + r) * 256 + k0;
        f32x4 q0 = *(const f32x4*)qp, q1 = *(const f32x4*)(qp + 4);
        f32x4 k0v = *(const f32x4*)kp, k1v = *(const f32x4*)(kp + 4);
        f32x4 e0v = *(const f32x4*)ep, e1v = *(const f32x4*)(ep + 4);
#pragma unroll
        for (int j = 0; j < 4; ++j) {
          v[j]     = (half_t)(SCALE_QK * q0[j] * k0v[j] + e0v[j]);
          v[4 + j] = (half_t)(SCALE_QK * q1[j] * k1v[j] + e1v[j]);
        }
      }
      *(f16x8*)(ne5 + r * 512 + ((k0 * 2) ^ ((r & 7) << 4))) = v;
    }
    __syncthreads();
    f32x4 acc1[2][2];
    run_gemm<2, 8, 2, 256, 256>(slot + OFF_EOT, ne5, acc1);
    __syncthreads();  // all waves done reading ne5 (aef overlays it)
    {
      const float* eob = p.eo_b + (size_t)lyr * 256;
#pragma unroll
      for (int n = 0; n < 2; ++n) {
        const int col = (n * 8 + wv) * 16 + l15;
        const float bcol = eob[col];
#pragma unroll
        for (int m = 0; m < 2; ++m)
#pragma unroll
          for (int r4 = 0; r4 < 4; ++r4) {
            const int row = m * 16 + kg * 4 + r4;
            if (row < NNODE) {
              aef[row * 257 + col] = fmaxf(acc1[n][m][r4] + bcol, 0.f) + e_in[(rowbase + row) * 256 + col];
            } else {
              aef[row * 257 + col] = 0.f;
              *(half_t*)(ae16 + row * 512 + ((col * 2) ^ ((row & 7) << 4))) = (half_t)0.f;
            }
          }
      }
    }
    __syncthreads();
    {  // LN1e -> aef (in place) + ae16
      const float* g = p.ln1e_g + (size_t)lyr * 256;
      const float* bv = p.ln1e_b + (size_t)lyr * 256;
      for (int r = wv; r < NNODE; r += 8) {
        float x[4];
#pragma unroll
        for (int j = 0; j < 4; ++j) x[j] = aef[r * 257 + lane * 4 + j];
        float s = x[0] + x[1] + x[2] + x[3];
        float s2 = x[0]*x[0] + x[1]*x[1] + x[2]*x[2] + x[3]*x[3];
#pragma unroll
        for (int off = 32; off; off >>= 1) { s += __shfl_xor(s, off); s2 += __shfl_xor(s2, off); }
        float mean = s * (1.f / 256.f);
        float rstd = rsqrtf(s2 * (1.f / 256.f) - mean * mean + 1e-5f);
        f16x4 hv;
#pragma unroll
        for (int j = 0; j < 4; ++j) {
          int c = lane * 4 + j;
          float y = (x[j] - mean) * rstd * g[c] + bv[c];
          aef[r * 257 + c] = y;
          hv[j] = (half_t)y;
        }
        *(f16x4*)(ae16 + r * 512 + ((lane * 8) ^ ((r & 7) << 4))) = hv;
      }
    }
    __syncthreads();
    {
      f32x4 acc2[8][2];
      run_gemm<8, 8, 2, 256, 256>(slot + OFF_ME1T, ae16, acc2);
      const float* mb1 = p.me_b1 + (size_t)lyr * 1024;
#pragma unroll
      for (int n = 0; n < 8; ++n) {
        const int col = (n * 8 + wv) * 16 + l15;
        const float bcol = mb1[col];
#pragma unroll
        for (int m = 0; m < 2; ++m)
#pragma unroll
          for (int r4 = 0; r4 < 4; ++r4) {
            const int row = m * 16 + kg * 4 + r4;
            float val = (row < NNODE) ? fmaxf(acc2[n][m][r4] + bcol, 0.f) : 0.f;
            *(half_t*)(hT + row * 2048 + ((col * 2) ^ ((row & 7) << 4))) = (half_t)val;
          }
      }
    }
    __syncthreads();
    {
      f32x4 acc3[2][2];
      run_gemm<2, 32, 2, 1024, 1024>(slot + OFF_ME2T, hT, acc3);
      const float* mb2 = p.me_b2 + (size_t)lyr * 256;
#pragma unroll
      for (int n = 0; n < 2; ++n) {
        const int col = (n * 8 + wv) * 16 + l15;
        const float bcol = mb2[col];
#pragma unroll
        for (int m = 0; m < 2; ++m)
#pragma unroll
          for (int r4 = 0; r4 < 4; ++r4) {
            const int row = m * 16 + kg * 4 + r4;
            if (row < NNODE)
              aef[row * 257 + col] += acc3[n][m][r4] + bcol;
          }
      }
    }
    __syncthreads();
    {  // LN2e -> e_out
      const float* g = p.ln2e_g + (size_t)lyr * 256;
      const float* bv = p.ln2e_b + (size_t)lyr * 256;
      for (int r = wv; r < NNODE; r += 8) {
        float x[4];
#pragma unroll
        for (int j = 0; j < 4; ++j) x[j] = aef[r * 257 + lane * 4 + j];
        float s = x[0] + x[1] + x[2] + x[3];
        float s2 = x[0]*x[0] + x[1]*x[1] + x[2]*x[2] + x[3]*x[3];
#pragma unroll
        for (int off = 32; off; off >>= 1) { s += __shfl_xor(s, off); s2 += __shfl_xor(s2, off); }
        float mean = s * (1.f / 256.f);
        float rstd = rsqrtf(s2 * (1.f / 256.f) - mean * mean + 1e-5f);
#pragma unroll
        for (int j = 0; j < 4; ++j) {
          int c = lane * 4 + j;
          e_out[(rowbase + r) * 256 + c] = (x[j] - mean) * rstd * g[c] + bv[c];
        }
      }
    }
  } else if (bid < 104) {
    // ---------------- node path: (b, half), 12 rows ----------------
    const int nb = bid - 96, b = nb >> 1, hf = nb & 1, i0 = hf * 12;
    float* kb_ = (float*)smem;         // [24][256]
    float* vb_ = kb_ + 6144;           // [24][256]
    float* qb_ = vb_ + 6144;           // [12][256]
    float* sc = qb_ + 3072;            // [12][24][8]
    float* wvb = sc + 2304;            // [12][256]
    char* aT = (char*)(wvb + 3072);    // [16][256] f16
    float* anf = (float*)smem;         // [16][257] (overlays kb_ later)
    char* an16 = smem + 16448;
    char* hN = smem + 24640;           // [16][1024] f16
    char* nc16 = smem + 57408;         // [16][256] f16

    for (int idx = tid; idx < 24 * 256; idx += 512) {
      int j = idx >> 8, d = idx & 255;
      kb_[idx] = qkv_in[(size_t)(b * NNODE + j) * 768 + 256 + d];
      vb_[idx] = qkv_in[(size_t)(b * NNODE + j) * 768 + 512 + d];
    }
    for (int idx = tid; idx < 12 * 256; idx += 512) {
      int ii = idx >> 8, d = idx & 255;
      qb_[idx] = qkv_in[(size_t)(b * NNODE + i0 + ii) * 768 + d];
    }
    __syncthreads();
    for (int pr = tid; pr < 12 * 24; pr += 512) {
      int il = pr / 24, j = pr % 24;
      const float* ep = e_in + ((size_t)(b * NNODE + i0 + il) * NNODE + j) * 256;
#pragma unroll
      for (int hh = 0; hh < 8; ++hh) {
        float dsum = 0.f, es = 0.f;
        for (int d = 0; d < 32; ++d) {
          dsum += qb_[il * 256 + hh * 32 + d] * kb_[j * 256 + hh * 32 + d];
          es += ep[hh * 32 + d];
        }
        sc[(il * 24 + j) * 8 + hh] = SCALE_QK * dsum + es;
      }
    }
    __syncthreads();
    for (int pr = tid; pr < 12 * 8; pr += 512) {
      int il = pr >> 3, hh = pr & 7;
      float mx = -1e30f;
      for (int j = 0; j < 24; ++j) mx = fmaxf(mx, sc[(il * 24 + j) * 8 + hh]);
      float ex[24]; float ssum = 0.f;
#pragma unroll
      for (int j = 0; j < 24; ++j) { ex[j] = expf(sc[(il * 24 + j) * 8 + hh] - mx); ssum += ex[j]; }
      float inv = 1.f / ssum;
#pragma unroll
      for (int j = 0; j < 24; ++j) sc[(il * 24 + j) * 8 + hh] = ex[j] * inv;
    }
    __syncthreads();
    for (int idx = tid; idx < 12 * 256; idx += 512) {
      int il = idx >> 8, d = idx & 255, hh = d >> 5;
      float s = 0.f;
#pragma unroll
      for (int j = 0; j < 24; ++j) s += sc[(il * 24 + j) * 8 + hh] * vb_[j * 256 + d];
      wvb[idx] = s;
    }
    __syncthreads();
    for (int idx = tid; idx < 16 * 32; idx += 512) {
      int r = idx >> 5, kb2 = idx & 31, k0 = kb2 * 8;
      f16x8 v;
#pragma unroll
      for (int j = 0; j < 8; ++j) v[j] = (half_t)((r < 12) ? wvb[r * 256 + k0 + j] : 0.f);
      *(f16x8*)(aT + r * 512 + ((k0 * 2) ^ ((r & 7) << 4))) = v;
    }
    __syncthreads();
    {
      f32x4 acca[2][1];
      run_gemm<2, 8, 1, 256, 256>(slot + OFF_NOT, aT, acca);
      const float* nob = p.no_b + (size_t)lyr * 256;
#pragma unroll
      for (int n = 0; n < 2; ++n) {
        const int col = (n * 8 + wv) * 16 + l15;
#pragma unroll
        for (int r4 = 0; r4 < 4; ++r4) {
          const int row = kg * 4 + r4;
          if (row < 12) {
            anf[row * 257 + col] = acca[n][0][r4] + nob[col] + n_in[(size_t)(b * NNODE + i0 + row) * 256 + col];
          } else {
            anf[row * 257 + col] = 0.f;
            *(half_t*)(an16 + row * 512 + ((col * 2) ^ ((row & 7) << 4))) = (half_t)0.f;
          }
        }
      }
    }
    __syncthreads();
    {  // LN1n -> anf + an16
      const float* g = p.ln1n_g + (size_t)lyr * 256;
      const float* bv = p.ln1n_b + (size_t)lyr * 256;
      for (int r = wv; r < 12; r += 8) {
        float x[4];
#pragma unroll
        for (int j = 0; j < 4; ++j) x[j] = anf[r * 257 + lane * 4 + j];
        float s = x[0] + x[1] + x[2] + x[3];
        float s2 = x[0]*x[0] + x[1]*x[1] + x[2]*x[2] + x[3]*x[3];
#pragma unroll
        for (int off = 32; off; off >>= 1) { s += __shfl_xor(s, off); s2 += __shfl_xor(s2, off); }
        float mean = s * (1.f / 256.f);
        float rstd = rsqrtf(s2 * (1.f / 256.f) - mean * mean + 1e-5f);
        f16x4 hv;
#pragma unroll
        for (int j = 0; j < 4; ++j) {
          int c = lane * 4 + j;
          float y = (x[j] - mean) * rstd * g[c] + bv[c];
          anf[r * 257 + c] = y;
          hv[j] = (half_t)y;
        }
        *(f16x4*)(an16 + r * 512 + ((lane * 8) ^ ((r & 7) << 4))) = hv;
      }
    }
    __syncthreads();
    {
      f32x4 accm[8][1];
      run_gemm<8, 8, 1, 256, 256>(slot + OFF_MN1T, an16, accm);
      const float* mb1 = p.mn_b1 + (size_t)lyr * 1024;
#pragma unroll
      for (int n = 0; n < 8; ++n) {
        const int col = (n * 8 + wv) * 16 + l15;
        const float bcol = mb1[col];
#pragma unroll
        for (int r4 = 0; r4 < 4; ++r4) {
          const int row = kg * 4 + r4;
          float val = (row < 12) ? fmaxf(accm[n][0][r4] + bcol, 0.f) : 0.f;
          *(half_t*)(hN + row * 2048 + ((col * 2) ^ ((row & 7) << 4))) = (half_t)val;
        }
      }
    }
    __syncthreads();
    {
      f32x4 acc2n[2][1];
      run_gemm<2, 32, 1, 1024, 1024>(slot + OFF_MN2T, hN, acc2n);
      const float* mb2 = p.mn_b2 + (size_t)lyr * 256;
#pragma unroll
      for (int n = 0; n < 2; ++n) {
        const int col = (n * 8 + wv) * 16 + l15;
#pragma unroll
        for (int r4 = 0; r4 < 4; ++r4) {
          const int row = kg * 4 + r4;
          if (row < 12)
            anf[row * 257 + col] += acc2n[n][0][r4] + mb2[col];
          else
            *(half_t*)(nc16 + row * 512 + ((col * 2) ^ ((row & 7) << 4))) = (half_t)0.f;
        }
      }
    }
    __syncthreads();
    {  // LN2n -> n_out + nc16
      const float* g = p.ln2n_g + (size_t)lyr * 256;
      const float* bv = p.ln2n_b + (size_t)lyr * 256;
      const float* cb = ws + WS_C + b * 256;
      for (int r = wv; r < 12; r += 8) {
        float x[4];
#pragma unroll
        for (int j = 0; j < 4; ++j) x[j] = anf[r * 257 + lane * 4 + j];
        float s = x[0] + x[1] + x[2] + x[3];
        float s2 = x[0]*x[0] + x[1]*x[1] + x[2]*x[2] + x[3]*x[3];
#pragma unroll
        for (int off = 32; off; off >>= 1) { s += __shfl_xor(s, off); s2 += __shfl_xor(s2, off); }
        float mean = s * (1.f / 256.f);
        float rstd = rsqrtf(s2 * (1.f / 256.f) - mean * mean + 1e-5f);
        f16x4 hv;
#pragma unroll
        for (int j = 0; j < 4; ++j) {
          int c = lane * 4 + j;
          float y = (x[j] - mean) * rstd * g[c] + bv[c];
          n_out[(size_t)(b * NNODE + i0 + r) * 256 + c] = y;
          hv[j] = (half_t)(y + cb[c]);
        }
        *(f16x4*)(nc16 + r * 512 + ((lane * 8) ^ ((r & 7) << 4))) = hv;
      }
    }
    __syncthreads();
    if (lyr + 1 < NLAYER) {
      f32x4 accq[6][1];
      run_gemm<6, 8, 1, 256, 256>(wt + (size_t)((lyr + 1) % 3) * SLOT_F16 + OFF_QKVT, nc16, accq);
      const float* qb = p.qkv_b + (size_t)(lyr + 1) * 768;
#pragma unroll
      for (int n = 0; n < 6; ++n) {
        const int col = (n * 8 + wv) * 16 + l15;
#pragma unroll
        for (int r4 = 0; r4 < 4; ++r4) {
          const int row = kg * 4 + r4;
          if (row < 12)
            qkv_out[(size_t)(b * NNODE + i0 + row) * 768 + col] = accq[n][0][r4] + qb[col];
        }
      }
    }
  } else {
    // ---------------- converters: produce f16 W^T for layer lyr+2 ----------------
    if (lyr + 2 < NLAYER) {
      half_t* dslot = wt + (size_t)((lyr + 2) % 3) * SLOT_F16;
      for (int tile = bid - 104; tile < 336; tile += 24)
        conv_layer_tile(p, dslot, lyr + 2, tile, smem);
    }
  }
}

// ================= output heads =====================
__global__ __launch_bounds__(512) void k_out(Params p) {
  __shared__ __align__(16) char smem[SMEM_BYTES];
  const int bid = blockIdx.x, tid = threadIdx.x;
  const int lane = tid & 63, wv = tid >> 6, l15 = lane & 15, kg = lane >> 4;
  float* ws = p.ws;
  half_t* wt = (half_t*)(ws + WS_WTF);
  const float* e0 = ws + WS_E;   // final parity 0
  const float* n0 = ws + WS_N;
  if (bid < 96) {
    const int b = bid / NNODE, i = bid % NNODE;
    char* A16 = smem;                       // [32][256] f16
    float* h2f = (float*)(smem + 16384);    // [32][257]
    for (int idx = tid; idx < 32 * 32; idx += 512) {
      int r = idx >> 5, kb = idx & 31, k0 = kb * 8;
      f16x8 v;
#pragma unroll
      for (int j = 0; j < 8; ++j) v[j] = (half_t)0.f;
      if (r < NNODE) {
        const float* ep = e0 + ((size_t)(b * NNODE + i) * NNODE + r) * 256 + k0;
        f32x4 a = *(const f32x4*)ep, b4 = *(const f32x4*)(ep + 4);
#pragma unroll
        for (int j = 0; j < 4; ++j) { v[j] = (half_t)a[j]; v[4 + j] = (half_t)b4[j]; }
      }
      *(f16x8*)(A16 + r * 512 + ((k0 * 2) ^ ((r & 7) << 4))) = v;
    }
    __syncthreads();
    f32x4 acc[2][2];
    run_gemm<2, 8, 2, 256, 256>(wt + OFF_OUTE1T, A16, acc);
#pragma unroll
    for (int n = 0; n < 2; ++n) {
      const int col = (n * 8 + wv) * 16 + l15;
#pragma unroll
      for (int m = 0; m < 2; ++m)
#pragma unroll
        for (int r4 = 0; r4 < 4; ++r4) {
          const int row = m * 16 + kg * 4 + r4;
          h2f[row * 257 + col] = (row < NNODE) ? fmaxf(acc[n][m][r4] + p.outE_b1[col], 0.f) : 0.f;
        }
    }
    __syncthreads();
    for (int pr = tid; pr < 24 * 12; pr += 512) {
      int j = pr / 12, oc = pr % 12;
      float s = p.outE_b2[oc];
      for (int k = 0; k < 256; ++k) s += h2f[j * 257 + k] * p.outE_w2[k * 12 + oc];
      p.out[1248 + ((size_t)(b * NNODE + i) * NNODE + j) * 12 + oc] = s;
    }
  } else {
    const int nb = bid - 96, b = nb >> 1, hf = nb & 1, i0 = hf * 12;
    float* nl = (float*)smem;               // [12][257]
    float* t1f = (float*)(smem + 12544);    // [12][257]
    for (int idx = tid; idx < 12 * 256; idx += 512) {
      int r = idx >> 8, c = idx & 255;
      nl[r * 257 + c] = n0[(size_t)(b * NNODE + i0 + r) * 256 + c];
    }
    __syncthreads();
    {
      int col = tid & 255, rh = tid >> 8;
      float a6[6] = {0.f, 0.f, 0.f, 0.f, 0.f, 0.f};
      for (int k = 0; k < 256; ++k) {
        float w = p.outN_w1[(size_t)k * 256 + col];
#pragma unroll
        for (int r = 0; r < 6; ++r) a6[r] += nl[(rh * 6 + r) * 257 + k] * w;
      }
#pragma unroll
      for (int r = 0; r < 6; ++r)
        t1f[(rh * 6 + r) * 257 + col] = fmaxf(a6[r] + p.outN_b1[col], 0.f);
    }
    __syncthreads();
    for (int pr = tid; pr < 12 * 13; pr += 512) {
      int il = pr / 13, oc = pr % 13;
      float s = p.outN_b2[oc];
      for (int k = 0; k < 256; ++k) s += t1f[il * 257 + k] * p.outN_w2[k * 13 + oc];
      p.out[((size_t)(b * NNODE) + i0 + il) * 13 + oc] = s;
    }
  }
}

extern "C" void kernel_launch(void* const* d_in, const int* in_sizes, int n_in,
                              void* d_out, int out_size, void* d_ws, size_t ws_size,
                              hipStream_t stream) {
  (void)in_sizes; (void)n_in; (void)out_size; (void)ws_size;
  Params p;
  const float* const* fi = (const float* const*)d_in;
  p.nodes = fi[0]; p.edges = fi[1]; p.conds = (const int*)d_in[2];
  p.inN_w1 = fi[3]; p.inN_b1 = fi[4]; p.inN_w2 = fi[5]; p.inN_b2 = fi[6];
  p.inE_w1 = fi[7]; p.inE_b1 = fi[8]; p.inE_w2 = fi[9]; p.inE_b2 = fi[10];
  p.inC_w1 = fi[11]; p.inC_b1 = fi[12]; p.inC_w2 = fi[13]; p.inC_b2 = fi[14];
  p.qkv_w = fi[15]; p.qkv_b = fi[16]; p.no_w = fi[17]; p.no_b = fi[18];
  p.eo_w = fi[19]; p.eo_b = fi[20];
  p.ln1n_g = fi[21]; p.ln1n_b = fi[22]; p.ln1e_g = fi[23]; p.ln1e_b = fi[24];
  p.mn_w1 = fi[25]; p.mn_b1 = fi[26]; p.mn_w2 = fi[27]; p.mn_b2 = fi[28];
  p.me_w1 = fi[29]; p.me_b1 = fi[30]; p.me_w2 = fi[31]; p.me_b2 = fi[32];
  p.ln2n_g = fi[33]; p.ln2n_b = fi[34]; p.ln2e_g = fi[35]; p.ln2e_b = fi[36];
  p.outN_w1 = fi[37]; p.outN_b1 = fi[38]; p.outN_w2 = fi[39]; p.outN_b2 = fi[40];
  p.outE_w1 = fi[41]; p.outE_b1 = fi[42]; p.outE_w2 = fi[43]; p.outE_b2 = fi[44];
  p.ws = (float*)d_ws; p.out = (float*)d_out;

  k_embedA<<<dim3(68), dim3(512), 0, stream>>>(p);
  k_embedB<<<dim3(104), dim3(512), 0, stream>>>(p);
  for (int l = 0; l < NLAYER; ++l)
    k_layer<<<dim3(128), dim3(512), 0, stream>>>(p, l);
  k_out<<<dim3(104), dim3(512), 0, stream>>>(p);
}

// Round 2
// 5008.813 us; speedup vs baseline: 1.0832x; 1.0832x over previous
//
#include <hip/hip_runtime.h>

typedef _Float16 half_t;
typedef _Float16 f16x8 __attribute__((ext_vector_type(8)));
typedef _Float16 f16x4 __attribute__((ext_vector_type(4)));
typedef float f32x4 __attribute__((ext_vector_type(4)));

#define BB 4
#define NNODE 24
#define NLAYER 64
#define SCALE_QK 0.0625f

// ---- workspace layout (float offsets) ----
#define WS_C     0               // [4][256]
#define WS_N     1024            // 2 x [96][256]
#define N_STRIDE   24576
#define WS_QKV   50176           // 2 x [96][768]
#define QKV_STRIDE 73728
#define WS_E     197632          // 2 x [2304][256]
#define E_STRIDE   589824
#define WS_WTF   1377280         // f16 region (as float index)
// f16 offsets inside a slot
#define SLOT_F16 1376256
#define OFF_QKVT 0               // [768][256]
#define OFF_NOT  196608          // [256][256]
#define OFF_EOT  262144          // [256][256]
#define OFF_MN1T 327680          // [1024][256]
#define OFF_MN2T 589824          // [256][1024]
#define OFF_ME1T 851968          // [1024][256]
#define OFF_ME2T 1114112         // [256][1024]
#define OFF_INE2T  (3*SLOT_F16)          // [256][256]
#define OFF_OUTE1T (3*SLOT_F16 + 65536)  // [256][256]

#define SMEM_BYTES 114816

struct Params {
  const float *nodes, *edges; const int* conds;
  const float *inN_w1,*inN_b1,*inN_w2,*inN_b2;
  const float *inE_w1,*inE_b1,*inE_w2,*inE_b2;
  const float *inC_w1,*inC_b1,*inC_w2,*inC_b2;
  const float *qkv_w,*qkv_b,*no_w,*no_b,*eo_w,*eo_b;
  const float *ln1n_g,*ln1n_b,*ln1e_g,*ln1e_b;
  const float *mn_w1,*mn_b1,*mn_w2,*mn_b2,*me_w1,*me_b1,*me_w2,*me_b2;
  const float *ln2n_g,*ln2n_b,*ln2e_g,*ln2e_b;
  const float *outN_w1,*outN_b1,*outN_w2,*outN_b2,*outE_w1,*outE_b1,*outE_w2,*outE_b2;
  float* ws; float* out;
};

// ---- per-WG MFMA GEMM with PF-deep register pipeline on the B (weight) operand.
// A (f16, LDS, XOR-swizzled) x WT (f16 global [N][K]). 8 waves; wave wv owns
// n-tiles {n*8+wv}. acc[n][m] = 16x16 C-tile. PF: B-prefetch depth (rotating
// buffer, statically indexed under full unroll -> stays in VGPRs).
template<int NTW, int KT, int MT, int PF, int LDA, int LDB>
__device__ __forceinline__ void run_gemm(const half_t* __restrict__ WT,
                                         const char* __restrict__ A,
                                         f32x4 (&acc)[NTW][MT]) {
  static_assert(PF >= 1 && PF <= KT, "bad PF");
  const int lane = threadIdx.x & 63;
  const int wv = threadIdx.x >> 6;
  const int l15 = lane & 15;
  const int kg = lane >> 4;
  const half_t* base[NTW];
#pragma unroll
  for (int n = 0; n < NTW; ++n)
    base[n] = WT + (size_t)((n * 8 + wv) * 16 + l15) * LDB + kg * 8;
  f16x8 b[PF][NTW];
#pragma unroll
  for (int q = 0; q < PF; ++q)
#pragma unroll
    for (int n = 0; n < NTW; ++n)
      b[q][n] = *(const f16x8*)(base[n] + q * 32);
#pragma unroll
  for (int n = 0; n < NTW; ++n)
#pragma unroll
    for (int m = 0; m < MT; ++m) {
      f32x4 z = {0.f, 0.f, 0.f, 0.f};
      acc[n][m] = z;
    }
#pragma unroll
  for (int kt = 0; kt < KT; ++kt) {
    const int k0 = kt * 32 + kg * 8;
    f16x8 a[MT];
#pragma unroll
    for (int m = 0; m < MT; ++m) {
      const int row = m * 16 + l15;
      a[m] = *(const f16x8*)(A + row * (LDA * 2) + ((k0 * 2) ^ ((row & 7) << 4)));
    }
#pragma unroll
    for (int n = 0; n < NTW; ++n)
#pragma unroll
      for (int m = 0; m < MT; ++m)
        acc[n][m] = __builtin_amdgcn_mfma_f32_16x16x32_f16(a[m], b[kt % PF][n], acc[n][m], 0, 0, 0);
    if (kt + PF < KT) {
#pragma unroll
      for (int n = 0; n < NTW; ++n)
        b[kt % PF][n] = *(const f16x8*)(base[n] + (kt + PF) * 32);
    }
  }
}

// ---- 64x64 transpose+convert fp32 -> f16 tile ----
__device__ void conv_matrix_tile(const float* __restrict__ src, half_t* __restrict__ dst,
                                 int K, int Nn, int tk, int tn, char* smem) {
  float* tl = (float*)smem;  // [64][65]
  const int t = threadIdx.x;
  const int c = t & 63;
  const int r0 = t >> 6;
  for (int r = r0; r < 64; r += 8)
    tl[r * 65 + c] = src[(size_t)(tk * 64 + r) * Nn + tn * 64 + c];
  __syncthreads();
  for (int r = r0; r < 64; r += 8)
    dst[(size_t)(tn * 64 + r) * K + tk * 64 + c] = (half_t)tl[c * 65 + r];
  __syncthreads();
}

__device__ void conv_layer_tile(const Params& p, half_t* slot, int lw, int tile, char* smem) {
  if (tile < 48)       { conv_matrix_tile(p.qkv_w + (size_t)lw*196608, slot+OFF_QKVT, 256, 768, tile & 3, tile >> 2, smem); }
  else if (tile < 64)  { int t2 = tile-48;  conv_matrix_tile(p.no_w  + (size_t)lw*65536,  slot+OFF_NOT,  256, 256, t2 & 3,  t2 >> 2, smem); }
  else if (tile < 80)  { int t2 = tile-64;  conv_matrix_tile(p.eo_w  + (size_t)lw*65536,  slot+OFF_EOT,  256, 256, t2 & 3,  t2 >> 2, smem); }
  else if (tile < 144) { int t2 = tile-80;  conv_matrix_tile(p.mn_w1 + (size_t)lw*262144, slot+OFF_MN1T, 256, 1024, t2 & 3, t2 >> 2, smem); }
  else if (tile < 208) { int t2 = tile-144; conv_matrix_tile(p.mn_w2 + (size_t)lw*262144, slot+OFF_MN2T, 1024, 256, t2 & 15, t2 >> 4, smem); }
  else if (tile < 272) { int t2 = tile-208; conv_matrix_tile(p.me_w1 + (size_t)lw*262144, slot+OFF_ME1T, 256, 1024, t2 & 3, t2 >> 2, smem); }
  else                 { int t2 = tile-272; conv_matrix_tile(p.me_w2 + (size_t)lw*262144, slot+OFF_ME2T, 1024, 256, t2 & 15, t2 >> 4, smem); }
}

// ================= embed A: cond-MLP + convert W(0), W(1), inE_w2T, outE_w1T ===========
__global__ __launch_bounds__(512) void k_embedA(Params p) {
  __shared__ __align__(16) char smem[SMEM_BYTES];
  const int bid = blockIdx.x, tid = threadIdx.x;
  float* ws = p.ws;
  half_t* wt = (half_t*)(ws + WS_WTF);
  if (bid < 4) {
    const int b = bid;
    const int cond = p.conds[b];
    float* t1 = (float*)smem;
    if (tid < 256) t1[tid] = fmaxf(p.inC_w1[(size_t)cond * 256 + tid] + p.inC_b1[tid], 0.f);
    __syncthreads();
    if (tid < 256) {
      float s = p.inC_b2[tid];
      for (int k = 0; k < 256; ++k) s += t1[k] * p.inC_w2[(size_t)k * 256 + tid];
      ws[WS_C + b * 256 + tid] = fmaxf(s, 0.f);
    }
  } else {
    for (int job = bid - 4; job < 704; job += 128) {
      if (job < 336)      conv_layer_tile(p, wt, 0, job, smem);
      else if (job < 672) conv_layer_tile(p, wt + SLOT_F16, 1, job - 336, smem);
      else if (job < 688) { int t2 = job - 672; conv_matrix_tile(p.inE_w2,  wt + OFF_INE2T,  256, 256, t2 & 3, t2 >> 2, smem); }
      else                { int t2 = job - 688; conv_matrix_tile(p.outE_w1, wt + OFF_OUTE1T, 256, 256, t2 & 3, t2 >> 2, smem); }
    }
  }
}

// ================= embed B: edge embed (MFMA), node embed + qkv(0) =====================
__global__ __launch_bounds__(512) void k_embedB(Params p) {
  __shared__ __align__(16) char smem[SMEM_BYTES];
  const int bid = blockIdx.x, tid = threadIdx.x;
  const int lane = tid & 63, wv = tid >> 6, l15 = lane & 15, kg = lane >> 4;
  float* ws = p.ws;
  half_t* wt = (half_t*)(ws + WS_WTF);
  float* e0 = ws + WS_E;
  float* n0 = ws + WS_N;
  float* qkv0 = ws + WS_QKV;
  if (bid < 96) {
    const int b = bid / NNODE, i = bid % NNODE;
    float* eb = (float*)smem;        // [24][12]
    char* t16 = smem + 2048;         // [32][256] f16
    for (int idx = tid; idx < 24 * 12; idx += 512)
      eb[idx] = p.edges[((size_t)(b * NNODE + i) * NNODE + idx / 12) * 12 + idx % 12];
    __syncthreads();
    for (int idx = tid; idx < 32 * 32; idx += 512) {
      int r = idx >> 5, kb = idx & 31, k0 = kb * 8;
      f16x8 v;
#pragma unroll
      for (int j = 0; j < 8; ++j) v[j] = (half_t)0.f;
      if (r < NNODE) {
#pragma unroll
        for (int j = 0; j < 8; ++j) {
          int col = k0 + j;
          float s = p.inE_b1[col];
          for (int kk = 0; kk < 12; ++kk) s += eb[r * 12 + kk] * p.inE_w1[kk * 256 + col];
          v[j] = (half_t)fmaxf(s, 0.f);
        }
      }
      *(f16x8*)(t16 + r * 512 + ((k0 * 2) ^ ((r & 7) << 4))) = v;
    }
    __syncthreads();
    f32x4 acc[2][2];
    run_gemm<2, 8, 2, 8, 256, 256>(wt + OFF_INE2T, t16, acc);
#pragma unroll
    for (int n = 0; n < 2; ++n) {
      const int col = (n * 8 + wv) * 16 + l15;
#pragma unroll
      for (int m = 0; m < 2; ++m)
#pragma unroll
        for (int r4 = 0; r4 < 4; ++r4) {
          const int row = m * 16 + kg * 4 + r4;
          if (row < NNODE)
            e0[((size_t)(b * NNODE + i) * NNODE + row) * 256 + col] = fmaxf(acc[n][m][r4] + p.inE_b2[col], 0.f);
        }
    }
  } else {
    const int nb = bid - 96, b = nb >> 1, hf = nb & 1, i0 = hf * 12;
    float* nd = (float*)smem;            // [12][16]
    float* t1 = (float*)(smem + 1024);   // [12][257]
    char* nc16 = smem + 16384;           // [16][256] f16
    for (int idx = tid; idx < 12 * 13; idx += 512)
      nd[(idx / 13) * 16 + (idx % 13)] = p.nodes[(size_t)(b * NNODE + i0 + idx / 13) * 13 + idx % 13];
    __syncthreads();
    for (int idx = tid; idx < 12 * 256; idx += 512) {
      int r = idx >> 8, col = idx & 255;
      float s = p.inN_b1[col];
      for (int kk = 0; kk < 13; ++kk) s += nd[r * 16 + kk] * p.inN_w1[kk * 256 + col];
      t1[r * 257 + col] = fmaxf(s, 0.f);
    }
    __syncthreads();
    {
      int col = tid & 255, rh = tid >> 8;
      float a6[6] = {0.f, 0.f, 0.f, 0.f, 0.f, 0.f};
      for (int k = 0; k < 256; ++k) {
        float w = p.inN_w2[(size_t)k * 256 + col];
#pragma unroll
        for (int r = 0; r < 6; ++r) a6[r] += t1[(rh * 6 + r) * 257 + k] * w;
      }
      const float* cb = ws + WS_C + b * 256;
#pragma unroll
      for (int r = 0; r < 6; ++r) {
        int row = rh * 6 + r;
        float y = fmaxf(a6[r] + p.inN_b2[col], 0.f);
        n0[(size_t)(b * NNODE + i0 + row) * 256 + col] = y;
        *(half_t*)(nc16 + row * 512 + ((col * 2) ^ ((row & 7) << 4))) = (half_t)(y + cb[col]);
      }
      if (rh == 0)
        for (int row = 12; row < 16; ++row)
          *(half_t*)(nc16 + row * 512 + ((col * 2) ^ ((row & 7) << 4))) = (half_t)0.f;
    }
    __syncthreads();
    f32x4 accq[6][1];
    run_gemm<6, 8, 1, 4, 256, 256>(wt + OFF_QKVT, nc16, accq);
#pragma unroll
    for (int n = 0; n < 6; ++n) {
      const int col = (n * 8 + wv) * 16 + l15;
#pragma unroll
      for (int r4 = 0; r4 < 4; ++r4) {
        const int row = kg * 4 + r4;
        if (row < 12)
          qkv0[(size_t)(b * NNODE + i0 + row) * 768 + col] = accq[n][0][r4] + p.qkv_b[col];
      }
    }
  }
}

// ================= one transformer layer =====================
__global__ __launch_bounds__(512) void k_layer(Params p, int lyr) {
  __shared__ __align__(16) char smem[SMEM_BYTES];
  const int bid = blockIdx.x, tid = threadIdx.x;
  const int lane = tid & 63, wv = tid >> 6, l15 = lane & 15, kg = lane >> 4;
  const int pin = lyr & 1, pout = pin ^ 1;
  float* ws = p.ws;
  half_t* wt = (half_t*)(ws + WS_WTF);
  const float* qkv_in = ws + WS_QKV + pin * QKV_STRIDE;
  float* qkv_out = ws + WS_QKV + pout * QKV_STRIDE;
  const float* n_in = ws + WS_N + pin * N_STRIDE;
  float* n_out = ws + WS_N + pout * N_STRIDE;
  const float* e_in = ws + WS_E + pin * E_STRIDE;
  float* e_out = ws + WS_E + pout * E_STRIDE;
  const half_t* slot = wt + (size_t)(lyr % 3) * SLOT_F16;

  if (bid < 96) {
    // ---------------- edge path: one (b,i), 24 rows ----------------
    const int b = bid / NNODE, i = bid % NNODE;
    const size_t rowbase = (size_t)(b * NNODE + i) * NNODE;
    float* aef = (float*)smem;     // [32][257] f32 (overlays ne5 after GEMM1)
    char* ne5 = smem;              // [32][256] f16
    char* ae16 = smem + 32896;     // [32][256] f16
    char* hT = smem + 49280;       // [32][1024] f16

    for (int idx = tid; idx < 32 * 32; idx += 512) {
      int r = idx >> 5, kb = idx & 31, k0 = kb * 8;
      f16x8 v;
#pragma unroll
      for (int j = 0; j < 8; ++j) v[j] = (half_t)0.f;
      if (r < NNODE) {
        const float* qp = qkv_in + (size_t)(b * NNODE + i) * 768 + k0;
        const float* kp = qkv_in + (size_t)(b * NNODE + r) * 768 + 256 + k0;
        const float* ep = e_in + (rowbase + r) * 256 + k0;
        f32x4 q0 = *(const f32x4*)qp, q1 = *(const f32x4*)(qp + 4);
        f32x4 k0v = *(const f32x4*)kp, k1v = *(const f32x4*)(kp + 4);
        f32x4 e0v = *(const f32x4*)ep, e1v = *(const f32x4*)(ep + 4);
#pragma unroll
        for (int j = 0; j < 4; ++j) {
          v[j]     = (half_t)(SCALE_QK * q0[j] * k0v[j] + e0v[j]);
          v[4 + j] = (half_t)(SCALE_QK * q1[j] * k1v[j] + e1v[j]);
        }
      }
      *(f16x8*)(ne5 + r * 512 + ((k0 * 2) ^ ((r & 7) << 4))) = v;
    }
    __syncthreads();
    f32x4 acc1[2][2];
    run_gemm<2, 8, 2, 8, 256, 256>(slot + OFF_EOT, ne5, acc1);
    __syncthreads();  // all waves done reading ne5 (aef overlays it)
    {
      const float* eob = p.eo_b + (size_t)lyr * 256;
#pragma unroll
      for (int n = 0; n < 2; ++n) {
        const int col = (n * 8 + wv) * 16 + l15;
        const float bcol = eob[col];
#pragma unroll
        for (int m = 0; m < 2; ++m)
#pragma unroll
          for (int r4 = 0; r4 < 4; ++r4) {
            const int row = m * 16 + kg * 4 + r4;
            if (row < NNODE) {
              aef[row * 257 + col] = fmaxf(acc1[n][m][r4] + bcol, 0.f) + e_in[(rowbase + row) * 256 + col];
            } else {
              aef[row * 257 + col] = 0.f;
              *(half_t*)(ae16 + row * 512 + ((col * 2) ^ ((row & 7) << 4))) = (half_t)0.f;
            }
          }
      }
    }
    __syncthreads();
    {  // LN1e -> aef (in place) + ae16
      const float* g = p.ln1e_g + (size_t)lyr * 256;
      const float* bv = p.ln1e_b + (size_t)lyr * 256;
      for (int r = wv; r < NNODE; r += 8) {
        float x[4];
#pragma unroll
        for (int j = 0; j < 4; ++j) x[j] = aef[r * 257 + lane * 4 + j];
        float s = x[0] + x[1] + x[2] + x[3];
        float s2 = x[0]*x[0] + x[1]*x[1] + x[2]*x[2] + x[3]*x[3];
#pragma unroll
        for (int off = 32; off; off >>= 1) { s += __shfl_xor(s, off); s2 += __shfl_xor(s2, off); }
        float mean = s * (1.f / 256.f);
        float rstd = rsqrtf(s2 * (1.f / 256.f) - mean * mean + 1e-5f);
        f16x4 hv;
#pragma unroll
        for (int j = 0; j < 4; ++j) {
          int c = lane * 4 + j;
          float y = (x[j] - mean) * rstd * g[c] + bv[c];
          aef[r * 257 + c] = y;
          hv[j] = (half_t)y;
        }
        *(f16x4*)(ae16 + r * 512 + ((lane * 8) ^ ((r & 7) << 4))) = hv;
      }
    }
    __syncthreads();
    {
      f32x4 acc2[8][2];
      run_gemm<8, 8, 2, 3, 256, 256>(slot + OFF_ME1T, ae16, acc2);
      const float* mb1 = p.me_b1 + (size_t)lyr * 1024;
#pragma unroll
      for (int n = 0; n < 8; ++n) {
        const int col = (n * 8 + wv) * 16 + l15;
        const float bcol = mb1[col];
#pragma unroll
        for (int m = 0; m < 2; ++m)
#pragma unroll
          for (int r4 = 0; r4 < 4; ++r4) {
            const int row = m * 16 + kg * 4 + r4;
            float val = (row < NNODE) ? fmaxf(acc2[n][m][r4] + bcol, 0.f) : 0.f;
            *(half_t*)(hT + row * 2048 + ((col * 2) ^ ((row & 7) << 4))) = (half_t)val;
          }
      }
    }
    __syncthreads();
    {
      f32x4 acc3[2][2];
      run_gemm<2, 32, 2, 8, 1024, 1024>(slot + OFF_ME2T, hT, acc3);
      const float* mb2 = p.me_b2 + (size_t)lyr * 256;
#pragma unroll
      for (int n = 0; n < 2; ++n) {
        const int col = (n * 8 + wv) * 16 + l15;
        const float bcol = mb2[col];
#pragma unroll
        for (int m = 0; m < 2; ++m)
#pragma unroll
          for (int r4 = 0; r4 < 4; ++r4) {
            const int row = m * 16 + kg * 4 + r4;
            if (row < NNODE)
              aef[row * 257 + col] += acc3[n][m][r4] + bcol;
          }
      }
    }
    __syncthreads();
    {  // LN2e -> e_out
      const float* g = p.ln2e_g + (size_t)lyr * 256;
      const float* bv = p.ln2e_b + (size_t)lyr * 256;
      for (int r = wv; r < NNODE; r += 8) {
        float x[4];
#pragma unroll
        for (int j = 0; j < 4; ++j) x[j] = aef[r * 257 + lane * 4 + j];
        float s = x[0] + x[1] + x[2] + x[3];
        float s2 = x[0]*x[0] + x[1]*x[1] + x[2]*x[2] + x[3]*x[3];
#pragma unroll
        for (int off = 32; off; off >>= 1) { s += __shfl_xor(s, off); s2 += __shfl_xor(s2, off); }
        float mean = s * (1.f / 256.f);
        float rstd = rsqrtf(s2 * (1.f / 256.f) - mean * mean + 1e-5f);
#pragma unroll
        for (int j = 0; j < 4; ++j) {
          int c = lane * 4 + j;
          e_out[(rowbase + r) * 256 + c] = (x[j] - mean) * rstd * g[c] + bv[c];
        }
      }
    }
  } else if (bid < 104) {
    // ---------------- node path: (b, half), 12 rows ----------------
    const int nb = bid - 96, b = nb >> 1, hf = nb & 1, i0 = hf * 12;
    // k/v staged with stride 260 (bank offset 65j mod 32 = j -> conflict-free f32x4)
    float* kb_ = (float*)smem;         // [24][260]
    float* vb_ = kb_ + 6240;           // [24][260]
    float* qb_ = vb_ + 6240;           // [12][256]
    float* sc = qb_ + 3072;            // [12][24][8]
    float* wvb = sc + 2304;            // [12][256]
    char* aT = (char*)(wvb + 3072);    // [16][256] f16
    float* anf = (float*)smem;         // [16][257] (overlays kb_ later)
    char* an16 = smem + 16448;
    char* hN = smem + 24640;           // [16][1024] f16
    char* nc16 = smem + 57408;         // [16][256] f16

    for (int idx = tid; idx < 24 * 256; idx += 512) {
      int j = idx >> 8, d = idx & 255;
      kb_[j * 260 + d] = qkv_in[(size_t)(b * NNODE + j) * 768 + 256 + d];
      vb_[j * 260 + d] = qkv_in[(size_t)(b * NNODE + j) * 768 + 512 + d];
    }
    for (int idx = tid; idx < 12 * 256; idx += 512) {
      int ii = idx >> 8, d = idx & 255;
      qb_[idx] = qkv_in[(size_t)(b * NNODE + i0 + ii) * 768 + d];
    }
    __syncthreads();
    for (int pr = tid; pr < 12 * 24; pr += 512) {
      int il = pr / 24, j = pr % 24;
      const f32x4* ep = (const f32x4*)(e_in + ((size_t)(b * NNODE + i0 + il) * NNODE + j) * 256);
      const f32x4* qv = (const f32x4*)(qb_ + il * 256);
      const f32x4* kv = (const f32x4*)(kb_ + j * 260);
      float dsum[8], es[8];
#pragma unroll
      for (int hh = 0; hh < 8; ++hh) { dsum[hh] = 0.f; es[hh] = 0.f; }
#pragma unroll
      for (int vq = 0; vq < 64; ++vq) {
        f32x4 e4 = ep[vq];
        f32x4 q4 = qv[vq];
        f32x4 k4 = kv[vq];
        es[vq >> 3] += e4[0] + e4[1] + e4[2] + e4[3];
        dsum[vq >> 3] += q4[0]*k4[0] + q4[1]*k4[1] + q4[2]*k4[2] + q4[3]*k4[3];
      }
#pragma unroll
      for (int hh = 0; hh < 8; ++hh)
        sc[(il * 24 + j) * 8 + hh] = SCALE_QK * dsum[hh] + es[hh];
    }
    __syncthreads();
    for (int pr = tid; pr < 12 * 8; pr += 512) {
      int il = pr >> 3, hh = pr & 7;
      float mx = -1e30f;
      for (int j = 0; j < 24; ++j) mx = fmaxf(mx, sc[(il * 24 + j) * 8 + hh]);
      float ex[24]; float ssum = 0.f;
#pragma unroll
      for (int j = 0; j < 24; ++j) { ex[j] = expf(sc[(il * 24 + j) * 8 + hh] - mx); ssum += ex[j]; }
      float inv = 1.f / ssum;
#pragma unroll
      for (int j = 0; j < 24; ++j) sc[(il * 24 + j) * 8 + hh] = ex[j] * inv;
    }
    __syncthreads();
    for (int idx = tid; idx < 12 * 256; idx += 512) {
      int il = idx >> 8, d = idx & 255, hh = d >> 5;
      float s = 0.f;
#pragma unroll
      for (int j = 0; j < 24; ++j) s += sc[(il * 24 + j) * 8 + hh] * vb_[j * 260 + d];
      wvb[idx] = s;
    }
    __syncthreads();
    for (int idx = tid; idx < 16 * 32; idx += 512) {
      int r = idx >> 5, kb2 = idx & 31, k0 = kb2 * 8;
      f16x8 v;
#pragma unroll
      for (int j = 0; j < 8; ++j) v[j] = (half_t)((r < 12) ? wvb[r * 256 + k0 + j] : 0.f);
      *(f16x8*)(aT + r * 512 + ((k0 * 2) ^ ((r & 7) << 4))) = v;
    }
    __syncthreads();
    {
      f32x4 acca[2][1];
      run_gemm<2, 8, 1, 8, 256, 256>(slot + OFF_NOT, aT, acca);
      const float* nob = p.no_b + (size_t)lyr * 256;
#pragma unroll
      for (int n = 0; n < 2; ++n) {
        const int col = (n * 8 + wv) * 16 + l15;
#pragma unroll
        for (int r4 = 0; r4 < 4; ++r4) {
          const int row = kg * 4 + r4;
          if (row < 12) {
            anf[row * 257 + col] = acca[n][0][r4] + nob[col] + n_in[(size_t)(b * NNODE + i0 + row) * 256 + col];
          } else {
            anf[row * 257 + col] = 0.f;
            *(half_t*)(an16 + row * 512 + ((col * 2) ^ ((row & 7) << 4))) = (half_t)0.f;
          }
        }
      }
    }
    __syncthreads();
    {  // LN1n -> anf + an16
      const float* g = p.ln1n_g + (size_t)lyr * 256;
      const float* bv = p.ln1n_b + (size_t)lyr * 256;
      for (int r = wv; r < 12; r += 8) {
        float x[4];
#pragma unroll
        for (int j = 0; j < 4; ++j) x[j] = anf[r * 257 + lane * 4 + j];
        float s = x[0] + x[1] + x[2] + x[3];
        float s2 = x[0]*x[0] + x[1]*x[1] + x[2]*x[2] + x[3]*x[3];
#pragma unroll
        for (int off = 32; off; off >>= 1) { s += __shfl_xor(s, off); s2 += __shfl_xor(s2, off); }
        float mean = s * (1.f / 256.f);
        float rstd = rsqrtf(s2 * (1.f / 256.f) - mean * mean + 1e-5f);
        f16x4 hv;
#pragma unroll
        for (int j = 0; j < 4; ++j) {
          int c = lane * 4 + j;
          float y = (x[j] - mean) * rstd * g[c] + bv[c];
          anf[r * 257 + c] = y;
          hv[j] = (half_t)y;
        }
        *(f16x4*)(an16 + r * 512 + ((lane * 8) ^ ((r & 7) << 4))) = hv;
      }
    }
    __syncthreads();
    {
      f32x4 accm[8][1];
      run_gemm<8, 8, 1, 3, 256, 256>(slot + OFF_MN1T, an16, accm);
      const float* mb1 = p.mn_b1 + (size_t)lyr * 1024;
#pragma unroll
      for (int n = 0; n < 8; ++n) {
        const int col = (n * 8 + wv) * 16 + l15;
        const float bcol = mb1[col];
#pragma unroll
        for (int r4 = 0; r4 < 4; ++r4) {
          const int row = kg * 4 + r4;
          float val = (row < 12) ? fmaxf(accm[n][0][r4] + bcol, 0.f) : 0.f;
          *(half_t*)(hN + row * 2048 + ((col * 2) ^ ((row & 7) << 4))) = (half_t)val;
        }
      }
    }
    __syncthreads();
    {
      f32x4 acc2n[2][1];
      run_gemm<2, 32, 1, 8, 1024, 1024>(slot + OFF_MN2T, hN, acc2n);
      const float* mb2 = p.mn_b2 + (size_t)lyr * 256;
#pragma unroll
      for (int n = 0; n < 2; ++n) {
        const int col = (n * 8 + wv) * 16 + l15;
#pragma unroll
        for (int r4 = 0; r4 < 4; ++r4) {
          const int row = kg * 4 + r4;
          if (row < 12)
            anf[row * 257 + col] += acc2n[n][0][r4] + mb2[col];
          else
            *(half_t*)(nc16 + row * 512 + ((col * 2) ^ ((row & 7) << 4))) = (half_t)0.f;
        }
      }
    }
    __syncthreads();
    {  // LN2n -> n_out + nc16
      const float* g = p.ln2n_g + (size_t)lyr * 256;
      const float* bv = p.ln2n_b + (size_t)lyr * 256;
      const float* cb = ws + WS_C + b * 256;
      for (int r = wv; r < 12; r += 8) {
        float x[4];
#pragma unroll
        for (int j = 0; j < 4; ++j) x[j] = anf[r * 257 + lane * 4 + j];
        float s = x[0] + x[1] + x[2] + x[3];
        float s2 = x[0]*x[0] + x[1]*x[1] + x[2]*x[2] + x[3]*x[3];
#pragma unroll
        for (int off = 32; off; off >>= 1) { s += __shfl_xor(s, off); s2 += __shfl_xor(s2, off); }
        float mean = s * (1.f / 256.f);
        float rstd = rsqrtf(s2 * (1.f / 256.f) - mean * mean + 1e-5f);
        f16x4 hv;
#pragma unroll
        for (int j = 0; j < 4; ++j) {
          int c = lane * 4 + j;
          float y = (x[j] - mean) * rstd * g[c] + bv[c];
          n_out[(size_t)(b * NNODE + i0 + r) * 256 + c] = y;
          hv[j] = (half_t)(y + cb[c]);
        }
        *(f16x4*)(nc16 + r * 512 + ((lane * 8) ^ ((r & 7) << 4))) = hv;
      }
    }
    __syncthreads();
    if (lyr + 1 < NLAYER) {
      f32x4 accq[6][1];
      run_gemm<6, 8, 1, 4, 256, 256>(wt + (size_t)((lyr + 1) % 3) * SLOT_F16 + OFF_QKVT, nc16, accq);
      const float* qb = p.qkv_b + (size_t)(lyr + 1) * 768;
#pragma unroll
      for (int n = 0; n < 6; ++n) {
        const int col = (n * 8 + wv) * 16 + l15;
#pragma unroll
        for (int r4 = 0; r4 < 4; ++r4) {
          const int row = kg * 4 + r4;
          if (row < 12)
            qkv_out[(size_t)(b * NNODE + i0 + row) * 768 + col] = accq[n][0][r4] + qb[col];
        }
      }
    }
  } else {
    // ---------------- converters: produce f16 W^T for layer lyr+2 ----------------
    if (lyr + 2 < NLAYER) {
      half_t* dslot = wt + (size_t)((lyr + 2) % 3) * SLOT_F16;
      for (int tile = bid - 104; tile < 336; tile += 64)
        conv_layer_tile(p, dslot, lyr + 2, tile, smem);
    }
  }
}

// ================= output heads =====================
__global__ __launch_bounds__(512) void k_out(Params p) {
  __shared__ __align__(16) char smem[SMEM_BYTES];
  const int bid = blockIdx.x, tid = threadIdx.x;
  const int lane = tid & 63, wv = tid >> 6, l15 = lane & 15, kg = lane >> 4;
  float* ws = p.ws;
  half_t* wt = (half_t*)(ws + WS_WTF);
  const float* e0 = ws + WS_E;   // final parity 0
  const float* n0 = ws + WS_N;
  if (bid < 96) {
    const int b = bid / NNODE, i = bid % NNODE;
    char* A16 = smem;                       // [32][256] f16
    float* h2f = (float*)(smem + 16384);    // [32][257]
    for (int idx = tid; idx < 32 * 32; idx += 512) {
      int r = idx >> 5, kb = idx & 31, k0 = kb * 8;
      f16x8 v;
#pragma unroll
      for (int j = 0; j < 8; ++j) v[j] = (half_t)0.f;
      if (r < NNODE) {
        const float* ep = e0 + ((size_t)(b * NNODE + i) * NNODE + r) * 256 + k0;
        f32x4 a = *(const f32x4*)ep, b4 = *(const f32x4*)(ep + 4);
#pragma unroll
        for (int j = 0; j < 4; ++j) { v[j] = (half_t)a[j]; v[4 + j] = (half_t)b4[j]; }
      }
      *(f16x8*)(A16 + r * 512 + ((k0 * 2) ^ ((r & 7) << 4))) = v;
    }
    __syncthreads();
    f32x4 acc[2][2];
    run_gemm<2, 8, 2, 8, 256, 256>(wt + OFF_OUTE1T, A16, acc);
#pragma unroll
    for (int n = 0; n < 2; ++n) {
      const int col = (n * 8 + wv) * 16 + l15;
#pragma unroll
      for (int m = 0; m < 2; ++m)
#pragma unroll
        for (int r4 = 0; r4 < 4; ++r4) {
          const int row = m * 16 + kg * 4 + r4;
          h2f[row * 257 + col] = (row < NNODE) ? fmaxf(acc[n][m][r4] + p.outE_b1[col], 0.f) : 0.f;
        }
    }
    __syncthreads();
    for (int pr = tid; pr < 24 * 12; pr += 512) {
      int j = pr / 12, oc = pr % 12;
      float s = p.outE_b2[oc];
      for (int k = 0; k < 256; ++k) s += h2f[j * 257 + k] * p.outE_w2[k * 12 + oc];
      p.out[1248 + ((size_t)(b * NNODE + i) * NNODE + j) * 12 + oc] = s;
    }
  } else {
    const int nb = bid - 96, b = nb >> 1, hf = nb & 1, i0 = hf * 12;
    float* nl = (float*)smem;               // [12][257]
    float* t1f = (float*)(smem + 12544);    // [12][257]
    for (int idx = tid; idx < 12 * 256; idx += 512) {
      int r = idx >> 8, c = idx & 255;
      nl[r * 257 + c] = n0[(size_t)(b * NNODE + i0 + r) * 256 + c];
    }
    __syncthreads();
    {
      int col = tid & 255, rh = tid >> 8;
      float a6[6] = {0.f, 0.f, 0.f, 0.f, 0.f, 0.f};
      for (int k = 0; k < 256; ++k) {
        float w = p.outN_w1[(size_t)k * 256 + col];
#pragma unroll
        for (int r = 0; r < 6; ++r) a6[r] += nl[(rh * 6 + r) * 257 + k] * w;
      }
#pragma unroll
      for (int r = 0; r < 6; ++r)
        t1f[(rh * 6 + r) * 257 + col] = fmaxf(a6[r] + p.outN_b1[col], 0.f);
    }
    __syncthreads();
    for (int pr = tid; pr < 12 * 13; pr += 512) {
      int il = pr / 13, oc = pr % 13;
      float s = p.outN_b2[oc];
      for (int k = 0; k < 256; ++k) s += t1f[il * 257 + k] * p.outN_w2[k * 13 + oc];
      p.out[((size_t)(b * NNODE) + i0 + il) * 13 + oc] = s;
    }
  }
}

extern "C" void kernel_launch(void* const* d_in, const int* in_sizes, int n_in,
                              void* d_out, int out_size, void* d_ws, size_t ws_size,
                              hipStream_t stream) {
  (void)in_sizes; (void)n_in; (void)out_size; (void)ws_size;
  Params p;
  const float* const* fi = (const float* const*)d_in;
  p.nodes = fi[0]; p.edges = fi[1]; p.conds = (const int*)d_in[2];
  p.inN_w1 = fi[3]; p.inN_b1 = fi[4]; p.inN_w2 = fi[5]; p.inN_b2 = fi[6];
  p.inE_w1 = fi[7]; p.inE_b1 = fi[8]; p.inE_w2 = fi[9]; p.inE_b2 = fi[10];
  p.inC_w1 = fi[11]; p.inC_b1 = fi[12]; p.inC_w2 = fi[13]; p.inC_b2 = fi[14];
  p.qkv_w = fi[15]; p.qkv_b = fi[16]; p.no_w = fi[17]; p.no_b = fi[18];
  p.eo_w = fi[19]; p.eo_b = fi[20];
  p.ln1n_g = fi[21]; p.ln1n_b = fi[22]; p.ln1e_g = fi[23]; p.ln1e_b = fi[24];
  p.mn_w1 = fi[25]; p.mn_b1 = fi[26]; p.mn_w2 = fi[27]; p.mn_b2 = fi[28];
  p.me_w1 = fi[29]; p.me_b1 = fi[30]; p.me_w2 = fi[31]; p.me_b2 = fi[32];
  p.ln2n_g = fi[33]; p.ln2n_b = fi[34]; p.ln2e_g = fi[35]; p.ln2e_b = fi[36];
  p.outN_w1 = fi[37]; p.outN_b1 = fi[38]; p.outN_w2 = fi[39]; p.outN_b2 = fi[40];
  p.outE_w1 = fi[41]; p.outE_b1 = fi[42]; p.outE_w2 = fi[43]; p.outE_b2 = fi[44];
  p.ws = (float*)d_ws; p.out = (float*)d_out;

  k_embedA<<<dim3(132), dim3(512), 0, stream>>>(p);
  k_embedB<<<dim3(104), dim3(512), 0, stream>>>(p);
  for (int l = 0; l < NLAYER; ++l)
    k_layer<<<dim3(168), dim3(512), 0, stream>>>(p, l);
  k_out<<<dim3(104), dim3(512), 0, stream>>>(p);
}